// Round 11
// baseline (2439.414 us; speedup 1.0000x reference)
//
#include <hip/hip_runtime.h>

typedef unsigned short u16;
typedef unsigned int u32;
typedef __attribute__((ext_vector_type(8))) short short8v;   // 8 bf16
typedef __attribute__((ext_vector_type(4))) float f32x4;

#define MFMA16(a,b,c) __builtin_amdgcn_mfma_f32_16x16x32_bf16((a),(b),(c),0,0,0)

__device__ __forceinline__ u16 f2bf(float f){
  u32 u = __float_as_uint(f);
  return (u16)((u + 0x7fffu + ((u >> 16) & 1u)) >> 16);   // RNE
}
__device__ __forceinline__ float bf2f(u16 h){ return __uint_as_float(((u32)h) << 16); }
__device__ __forceinline__ float gelu_f(float x){ return 0.5f * x * (1.f + erff(x * 0.70710678118654752f)); }
__device__ __forceinline__ float sigm_f(float x){ return 1.f / (1.f + __expf(-x)); }
__device__ __forceinline__ void acc4(float4& a, const float4 b){ a.x+=b.x; a.y+=b.y; a.z+=b.z; a.w+=b.w; }

__device__ __forceinline__ void gl16(const void* g, void* l){
  __builtin_amdgcn_global_load_lds((const __attribute__((address_space(1))) u32*)g,
                                   (__attribute__((address_space(3))) u32*)l, 16, 0, 0);
}

// ---------------- fused cast fp32 -> bf16 (13 jobs incl comp) ----------------
struct CastJobs { const float* s[13]; u16* d[13]; int start[14]; };
__global__ __launch_bounds__(256) void cast_all_k(CastJobs J){
  int bx = blockIdx.x, j = 0;
  #pragma unroll
  for (int t = 0; t < 13; t++) if (bx >= J.start[t + 1]) j = t + 1;
  int i = (bx - J.start[j]) * 1024 + threadIdx.x * 4;
  float4 v = *(const float4*)(J.s[j] + i);
  ushort4 o; o.x = f2bf(v.x); o.y = f2bf(v.y); o.z = f2bf(v.z); o.w = f2bf(v.w);
  *(ushort4*)(J.d[j] + i) = o;
}

// ---------------- transpose-cast 1024x1024 fp32 -> bf16^T (attn_out_w) ----------------
__global__ __launch_bounds__(256) void tcast_k(const float* __restrict__ s, u16* __restrict__ d){
  __shared__ float tile[32][33];
  int bx = blockIdx.x & 31, by = blockIdx.x >> 5;
  int tx = threadIdx.x & 31, ty = threadIdx.x >> 5;
  #pragma unroll
  for (int i = 0; i < 4; i++)
    tile[ty + i * 8][tx] = s[(size_t)(by * 32 + ty + i * 8) * 1024 + bx * 32 + tx];
  __syncthreads();
  #pragma unroll
  for (int i = 0; i < 4; i++)
    d[(size_t)(bx * 32 + ty + i * 8) * 1024 + by * 32 + tx] = f2bf(tile[tx][ty + i * 8]);
}

// ---------------- transpose-cast gen_w2 [1024,2048] fp32 -> [2048,1024] bf16 ----------------
__global__ __launch_bounds__(256) void ttcast_k(const float* __restrict__ s, u16* __restrict__ d){
  __shared__ float tile[32][33];
  int cx = blockIdx.x & 63, ry = blockIdx.x >> 6;
  int tx = threadIdx.x & 31, ty = threadIdx.x >> 5;
  #pragma unroll
  for (int i = 0; i < 4; i++)
    tile[ty + i * 8][tx] = s[(size_t)(ry * 32 + ty + i * 8) * 2048 + cx * 32 + tx];
  __syncthreads();
  #pragma unroll
  for (int i = 0; i < 4; i++)
    d[(size_t)(cx * 32 + ty + i * 8) * 1024 + ry * 32 + tx] = f2bf(tile[tx][ty + i * 8]);
}

// ---------------- multi-job bf16 GEMM: C = A @ B^T (K=1024), per-job ldc ----------------
struct GJobs { const u16* A[5]; const u16* B[5]; u16* C[5]; int mb[5]; int nb[5]; int ldc[5]; };
__global__ __launch_bounds__(256) void gemmbb_k(GJobs J){
  int z = blockIdx.z;
  if ((int)blockIdx.x >= J.mb[z] || (int)blockIdx.y >= J.nb[z]) return;
  const u16* A = J.A[z]; const u16* B = J.B[z]; u16* C = J.C[z]; int ldc = J.ldc[z];
  __shared__ u16 As[128 * 64];
  __shared__ u16 Bs[128 * 64];
  int tid = threadIdx.x;
  int m0 = blockIdx.x * 128, n0 = blockIdx.y * 128;
  int w = tid >> 6, l = tid & 63, lr = l & 15, lk = l >> 4;
  int wm = (w >> 1) * 64, wn = (w & 1) * 64;
  f32x4 acc[4][4];
  #pragma unroll
  for (int i = 0; i < 4; i++)
    #pragma unroll
    for (int j = 0; j < 4; j++) acc[i][j] = (f32x4){0.f,0.f,0.f,0.f};
  for (int kc = 0; kc < 1024; kc += 64){
    #pragma unroll
    for (int r = 0; r < 4; r++){
      int s = tid + r * 256;
      int row = s >> 3, pp = s & 7;
      int lg = pp ^ (row & 7);
      gl16(A + (size_t)(m0 + row) * 1024 + kc + lg * 8, As + s * 8);
      gl16(B + (size_t)(n0 + row) * 1024 + kc + lg * 8, Bs + s * 8);
    }
    __syncthreads();
    #pragma unroll
    for (int kk = 0; kk < 2; kk++){
      short8v a[4], bb[4];
      #pragma unroll
      for (int mi = 0; mi < 4; mi++){
        int row = wm + mi * 16 + lr;
        int ph = (kk * 4 + lk) ^ (row & 7);
        a[mi] = *(const short8v*)(As + row * 64 + ph * 8);
      }
      #pragma unroll
      for (int ni = 0; ni < 4; ni++){
        int row = wn + ni * 16 + lr;
        int ph = (kk * 4 + lk) ^ (row & 7);
        bb[ni] = *(const short8v*)(Bs + row * 64 + ph * 8);
      }
      #pragma unroll
      for (int mi = 0; mi < 4; mi++)
        #pragma unroll
        for (int ni = 0; ni < 4; ni++)
          acc[mi][ni] = MFMA16(a[mi], bb[ni], acc[mi][ni]);
    }
    __syncthreads();
  }
  #pragma unroll
  for (int mi = 0; mi < 4; mi++)
    #pragma unroll
    for (int ni = 0; ni < 4; ni++)
      #pragma unroll
      for (int r = 0; r < 4; r++){
        int row = m0 + wm + mi * 16 + lk * 4 + r;
        int col = n0 + wn + ni * 16 + lr;
        C[(size_t)row * ldc + col] = f2bf(acc[mi][ni][r]);
      }
}

// ---------------- multi-job bias fold: out = base + W @ (v [+ v2]) ----------------
struct BJobs { const float* W[5]; const float* v[5]; const float* v2[5];
               const float* base[5]; float* out[5]; int start[6]; };
__global__ __launch_bounds__(256) void biasfold_k(BJobs J){
  int bx = blockIdx.x, j = 0;
  #pragma unroll
  for (int t = 0; t < 5; t++) if (bx >= J.start[t + 1]) j = t + 1;
  int row = (bx - J.start[j]) * 32 + (threadIdx.x >> 3);
  int l8 = threadIdx.x & 7;
  const float* wr = J.W[j] + (size_t)row * 1024;
  const float* v = J.v[j]; const float* v2 = J.v2[j];
  float acc = 0.f;
  #pragma unroll 8
  for (int kk = 0; kk < 32; kk++){
    int k = kk * 32 + l8 * 4;
    float4 wv = *(const float4*)(wr + k);
    float4 a = *(const float4*)(v + k);
    if (v2) acc4(a, *(const float4*)(v2 + k));
    acc += wv.x * a.x + wv.y * a.y + wv.z * a.z + wv.w * a.w;
  }
  acc += __shfl_xor(acc, 1); acc += __shfl_xor(acc, 2); acc += __shfl_xor(acc, 4);
  if (l8 == 0) J.out[j][row] = J.base[j][row] + acc;
}

// ---------------- init ----------------
__global__ __launch_bounds__(256) void init_k(const float* __restrict__ comp, float* ps0,
                                              float* outp, float* h0, float* c0, float* h1, float* c1){
  int i = blockIdx.x * 256 + threadIdx.x;       // 32768
  int b = i >> 10, hh = i & 1023;
  float v = comp[(size_t)b * 1048576 + hh];
  ps0[i] = v; outp[i] = v;
  h0[i] = 0.f; c0[i] = 0.f; h1[i] = 0.f; c1[i] = 0.f;
}

// ---------------- fused K/V GEMM (bf16). Kt:[b][hd][s], Vb:[b][h][s][d] ----------------
__global__ __launch_bounds__(256) void gemmkv_k(const u16* __restrict__ compb,
    const u16* __restrict__ Wk, const u16* __restrict__ Wv,
    const float* __restrict__ bk, const float* __restrict__ bv,
    u16* __restrict__ Kt, u16* __restrict__ Vb)
{
  __shared__ u16 Sh[16384];
  u16* As = Sh;
  u16* Bs = Sh + 8192;
  int tid = threadIdx.x;
  int x = blockIdx.x;
  int xcd = x & 7, p = x >> 3;
  int cpanel = xcd * 32 + (p >> 3);
  int wpanel = p & 7;
  int isK = (blockIdx.z != 0);
  const u16 *msrc, *nsrc; int m0, n0;
  if (!isK){ m0 = cpanel * 128; n0 = wpanel * 128; msrc = compb; nsrc = Wv; }
  else     { m0 = wpanel * 128; n0 = cpanel * 128; msrc = Wk;    nsrc = compb; }

  int w = tid >> 6, l = tid & 63, lr = l & 15, lk = l >> 4;
  int wm = (w >> 1) * 64, wn = (w & 1) * 64;
  f32x4 acc[4][4];
  #pragma unroll
  for (int i = 0; i < 4; i++)
    #pragma unroll
    for (int j = 0; j < 4; j++) acc[i][j] = (f32x4){0.f,0.f,0.f,0.f};

  for (int kc = 0; kc < 1024; kc += 64){
    #pragma unroll
    for (int r = 0; r < 4; r++){
      int s = tid + r * 256;
      int row = s >> 3, pp = s & 7;
      int lg = pp ^ (row & 7);
      gl16(msrc + (size_t)(m0 + row) * 1024 + kc + lg * 8, As + s * 8);
      gl16(nsrc + (size_t)(n0 + row) * 1024 + kc + lg * 8, Bs + s * 8);
    }
    __syncthreads();
    #pragma unroll
    for (int kk = 0; kk < 2; kk++){
      short8v a[4], bb[4];
      #pragma unroll
      for (int mi = 0; mi < 4; mi++){
        int row = wm + mi * 16 + lr;
        int ph = (kk * 4 + lk) ^ (row & 7);
        a[mi] = *(const short8v*)(As + row * 64 + ph * 8);
      }
      #pragma unroll
      for (int ni = 0; ni < 4; ni++){
        int row = wn + ni * 16 + lr;
        int ph = (kk * 4 + lk) ^ (row & 7);
        bb[ni] = *(const short8v*)(Bs + row * 64 + ph * 8);
      }
      #pragma unroll
      for (int mi = 0; mi < 4; mi++)
        #pragma unroll
        for (int ni = 0; ni < 4; ni++)
          acc[mi][ni] = MFMA16(a[mi], bb[ni], acc[mi][ni]);
    }
    __syncthreads();
  }
  #pragma unroll
  for (int mi = 0; mi < 4; mi++)
    #pragma unroll
    for (int ni = 0; ni < 4; ni++)
      #pragma unroll
      for (int r = 0; r < 4; r++){
        int row = wm + mi * 16 + lk * 4 + r;
        int col = wn + ni * 16 + lr;
        float bias = isK ? bk[m0 + row] : bv[n0 + col];
        Sh[row * 128 + col] = f2bf(acc[mi][ni][r] + bias);
      }
  __syncthreads();
  for (int i = tid; i < 2048; i += 256){
    int r = i >> 4, c8 = (i & 15) * 8;
    uint4 o = *(const uint4*)(Sh + r * 128 + c8);
    if (!isK){
      int bs = m0 + r, hd = n0 + c8;
      int b = bs >> 10, s = bs & 1023;
      int h = hd >> 6, d = hd & 63;
      *(uint4*)(Vb + ((size_t)(b * 16 + h) * 1024 + s) * 64 + d) = o;
    } else {
      int hd = m0 + r, bs = n0 + c8;
      int b = bs >> 10, s = bs & 1023;
      *(uint4*)(Kt + ((size_t)b * 1024 + hd) * 1024 + s) = o;
    }
  }
}

// ---------------- M=32, N=16 MFMA linear tile: X-sum path, Y path, LN'd Z path ----------------
struct LinSeg {
  const float* X0; const float* Xa; const float* Xb; const float* Xc;   // X path
  const u16* W1; int K1, ldx, ld1;
  const float* Y; const u16* W2; int K2, ld2;                          // Y path
  const float* Zp; const u16* WZ; int KZ, ldz, ldwz;                   // Z path (LN+gelu)
  const float* lng; const float* lnb; const float* lnstats;
  const float* b1; const float* b2;
  float* out; float* out2; int N, act, gate;   // act: 0 none, 1 gelu, 2 scale
  float scale;
  float* stats;
  const float* cprev; float* cout; float* hout;
};

__device__ __forceinline__ short8v pack8(float4 v0, float4 v1){
  short8v r;
  r[0]=(short)f2bf(v0.x); r[1]=(short)f2bf(v0.y); r[2]=(short)f2bf(v0.z); r[3]=(short)f2bf(v0.w);
  r[4]=(short)f2bf(v1.x); r[5]=(short)f2bf(v1.y); r[6]=(short)f2bf(v1.z); r[7]=(short)f2bf(v1.w);
  return r;
}

__device__ __forceinline__ short8v load_sum8(const LinSeg& S, int row, int kb){
  size_t o = (size_t)row * S.ldx + kb;
  float4 v0 = *(const float4*)(S.X0 + o);
  float4 v1 = *(const float4*)(S.X0 + o + 4);
  if (S.Xa){ acc4(v0, *(const float4*)(S.Xa + o)); acc4(v1, *(const float4*)(S.Xa + o + 4)); }
  if (S.Xb){ acc4(v0, *(const float4*)(S.Xb + o)); acc4(v1, *(const float4*)(S.Xb + o + 4)); }
  if (S.Xc){ acc4(v0, *(const float4*)(S.Xc + o)); acc4(v1, *(const float4*)(S.Xc + o + 4)); }
  return pack8(v0, v1);
}
__device__ __forceinline__ short8v load_y8(const float* p){
  return pack8(*(const float4*)(p), *(const float4*)(p + 4));
}
__device__ __forceinline__ short8v load_z8(const LinSeg& S, int row, int kb){
  size_t o = (size_t)row * S.ldz + kb;
  float4 v0 = *(const float4*)(S.Zp + o);
  float4 v1 = *(const float4*)(S.Zp + o + 4);
  float mu = S.lnstats[row] * (1.f / 2048.f);
  float ms = S.lnstats[32 + row] * (1.f / 2048.f);
  float rstd = rsqrtf(ms - mu * mu + 1e-5f);
  float4 g0 = *(const float4*)(S.lng + kb), g1 = *(const float4*)(S.lng + kb + 4);
  float4 b0 = *(const float4*)(S.lnb + kb), b1 = *(const float4*)(S.lnb + kb + 4);
  v0.x = gelu_f((v0.x - mu) * rstd * g0.x + b0.x);
  v0.y = gelu_f((v0.y - mu) * rstd * g0.y + b0.y);
  v0.z = gelu_f((v0.z - mu) * rstd * g0.z + b0.z);
  v0.w = gelu_f((v0.w - mu) * rstd * g0.w + b0.w);
  v1.x = gelu_f((v1.x - mu) * rstd * g1.x + b1.x);
  v1.y = gelu_f((v1.y - mu) * rstd * g1.y + b1.y);
  v1.z = gelu_f((v1.z - mu) * rstd * g1.z + b1.z);
  v1.w = gelu_f((v1.w - mu) * rstd * g1.w + b1.w);
  return pack8(v0, v1);
}

typedef float Red16[32][16];   // red[4][32][16] = 8KB

__device__ void lin_body(const LinSeg& S, int bi, int tid, Red16* red){
  int c0 = bi * 16, j0 = bi * 4;
  int w = tid >> 6, l = tid & 63, lr = l & 15, lk = l >> 4;
  int wc0 = S.gate ? ((lr >> 2) << 10) + j0 + (lr & 3) : c0 + lr;
  f32x4 acc[2];
  acc[0] = (f32x4){0.f,0.f,0.f,0.f};
  acc[1] = (f32x4){0.f,0.f,0.f,0.f};

  if (S.X0){
    int chunk = S.K1 >> 2;
    int kb0 = w * chunk + lk * 8;
    for (int kk = 0; kk < chunk; kk += 32){
      int kb = kb0 + kk;
      short8v a0 = load_sum8(S, lr, kb);
      short8v a1 = load_sum8(S, lr + 16, kb);
      short8v w0 = *(const short8v*)(S.W1 + (size_t)wc0 * S.ld1 + kb);
      acc[0] = MFMA16(a0, w0, acc[0]);
      acc[1] = MFMA16(a1, w0, acc[1]);
    }
  }
  if (S.Y){
    int chunk = S.K2 >> 2;
    int kb0 = w * chunk + lk * 8;
    for (int kk = 0; kk < chunk; kk += 32){
      int kb = kb0 + kk;
      short8v a0 = load_y8(S.Y + (size_t)lr * S.K2 + kb);
      short8v a1 = load_y8(S.Y + (size_t)(lr + 16) * S.K2 + kb);
      short8v w0 = *(const short8v*)(S.W2 + (size_t)wc0 * S.ld2 + kb);
      acc[0] = MFMA16(a0, w0, acc[0]);
      acc[1] = MFMA16(a1, w0, acc[1]);
    }
  }
  if (S.Zp){
    int chunk = S.KZ >> 2;
    int kb0 = w * chunk + lk * 8;
    for (int kk = 0; kk < chunk; kk += 32){
      int kb = kb0 + kk;
      short8v a0 = load_z8(S, lr, kb);
      short8v a1 = load_z8(S, lr + 16, kb);
      short8v w0 = *(const short8v*)(S.WZ + (size_t)wc0 * S.ldwz + kb);
      acc[0] = MFMA16(a0, w0, acc[0]);
      acc[1] = MFMA16(a1, w0, acc[1]);
    }
  }
  #pragma unroll
  for (int mi = 0; mi < 2; mi++)
    #pragma unroll
    for (int r = 0; r < 4; r++)
      red[w][mi * 16 + lk * 4 + r][lr] = acc[mi][r];
  __syncthreads();
  if (S.gate){
    if (tid < 128){
      int row = tid >> 2, j = tid & 3;
      float s[4];
      #pragma unroll
      for (int g = 0; g < 4; g++){
        float v = 0.f;
        #pragma unroll
        for (int ww = 0; ww < 4; ww++) v += red[ww][row][g * 4 + j];
        s[g] = v;
      }
      int gc = j0 + j;
      float gI = s[0] + S.b1[gc]        + S.b2[gc];
      float gF = s[1] + S.b1[1024 + gc] + S.b2[1024 + gc];
      float gG = s[2] + S.b1[2048 + gc] + S.b2[2048 + gc];
      float gO = s[3] + S.b1[3072 + gc] + S.b2[3072 + gc];
      int idx = row * 1024 + gc;
      float cN = sigm_f(gF) * S.cprev[idx] + sigm_f(gI) * tanhf(gG);
      S.cout[idx] = cN;
      S.hout[idx] = sigm_f(gO) * tanhf(cN);
    }
    return;
  }
  float vout[2]; int iout[2];
  int cnt = 0;
  for (int i = tid; i < 512; i += 256){
    int row = i >> 4, col = i & 15;
    float v = 0.f;
    #pragma unroll
    for (int ww = 0; ww < 4; ww++) v += red[ww][row][col];
    if (S.b1) v += S.b1[c0 + col];
    if (S.b2) v += S.b2[c0 + col];
    if (S.act == 1) v = gelu_f(v);
    else if (S.act == 2) v *= S.scale;
    S.out[(size_t)row * S.N + c0 + col] = v;
    if (S.out2) S.out2[(size_t)row * S.N + c0 + col] = v;
    vout[cnt] = v; iout[cnt] = i; cnt++;
  }
  if (S.stats){
    __syncthreads();
    float* rf = (float*)red;
    rf[iout[0]] = vout[0]; rf[512 + iout[0]] = vout[0] * vout[0];
    rf[iout[1]] = vout[1]; rf[512 + iout[1]] = vout[1] * vout[1];
    __syncthreads();
    if (tid < 32){
      float s = 0.f, s2 = 0.f;
      #pragma unroll
      for (int cc = 0; cc < 16; cc++){ s += rf[tid * 16 + cc]; s2 += rf[512 + tid * 16 + cc]; }
      atomicAdd(S.stats + tid, s);
      atomicAdd(S.stats + 32 + tid, s2);
    }
  }
}

__global__ __launch_bounds__(256) void linmulti_k(LinSeg s0, LinSeg s1, LinSeg s2, int n0, int n1){
  __shared__ float red[4][32][16];
  int bx = blockIdx.x, tid = threadIdx.x;
  if (bx < n0) lin_body(s0, bx, tid, red);
  else if (bx < n0 + n1) lin_body(s1, bx - n0, tid, red);
  else lin_body(s2, bx - n0 - n1, tid, red);
}

// ---------------- attention job ----------------
__device__ void attn_job(int bh, int tid, const float* q, const u16* Kt, const u16* Vb,
                         float* afull, float* ctx0, float* shf){
  float* qs = shf;            // 64
  float* sc = shf + 64;       // 1024
  float* rr = shf + 1088;     // 8
  float* ctxp = shf + 1096;   // 512
  int b = bh >> 4, h = bh & 15;
  if (tid < 64) qs[tid] = q[bh * 64 + tid];
  __syncthreads();
  const u32* kt = (const u32*)(Kt + (size_t)bh * 65536);
  float a0 = 0.f, a1 = 0.f, a2 = 0.f, a3 = 0.f;
  #pragma unroll 8
  for (int d = 0; d < 64; d++){
    float qd = qs[d];
    u32 p0 = kt[d * 512 + tid];
    u32 p1 = kt[d * 512 + tid + 256];
    a0 += qd * bf2f((u16)(p0 & 0xffff)); a1 += qd * bf2f((u16)(p0 >> 16));
    a2 += qd * bf2f((u16)(p1 & 0xffff)); a3 += qd * bf2f((u16)(p1 >> 16));
  }
  float mx = fmaxf(fmaxf(a0, a1), fmaxf(a2, a3));
  for (int o = 1; o < 64; o <<= 1) mx = fmaxf(mx, __shfl_xor(mx, o));
  if ((tid & 63) == 0) rr[tid >> 6] = mx;
  __syncthreads();
  mx = fmaxf(fmaxf(rr[0], rr[1]), fmaxf(rr[2], rr[3]));
  float e0 = __expf(a0 - mx), e1 = __expf(a1 - mx), e2 = __expf(a2 - mx), e3 = __expf(a3 - mx);
  float sm = e0 + e1 + e2 + e3;
  for (int o = 1; o < 64; o <<= 1) sm += __shfl_xor(sm, o);
  if ((tid & 63) == 0) rr[4 + (tid >> 6)] = sm;
  __syncthreads();
  sm = rr[4] + rr[5] + rr[6] + rr[7];
  float inv = 1.f / sm;
  float* ar = afull + (size_t)bh * 1024;
  float2 w0 = make_float2(e0 * inv, e1 * inv);
  float2 w1 = make_float2(e2 * inv, e3 * inv);
  *(float2*)(sc + 2 * tid) = w0;       *(float2*)(ar + 2 * tid) = w0;
  *(float2*)(sc + 512 + 2 * tid) = w1; *(float2*)(ar + 512 + 2 * tid) = w1;
  __syncthreads();
  int dd2 = tid & 31, chunk = tid >> 5;
  const u32* vp = (const u32*)(Vb + ((size_t)(b * 16 + h) * 1024 + chunk * 128) * 64) + dd2;
  const float* scp = sc + chunk * 128;
  float c0 = 0.f, c1 = 0.f;
  #pragma unroll 8
  for (int s = 0; s < 128; s++){
    u32 vv = vp[s * 32];
    float w = scp[s];
    c0 += w * bf2f((u16)(vv & 0xffff));
    c1 += w * bf2f((u16)(vv >> 16));
  }
  *(float2*)(ctxp + chunk * 64 + dd2 * 2) = make_float2(c0, c1);
  __syncthreads();
  if (tid < 64){
    float r = 0.f;
    #pragma unroll
    for (int c = 0; c < 8; c++) r += ctxp[c * 64 + tid];
    ctx0[bh * 64 + tid] = r;
  }
}

// ---------------- rule softmax + sel ----------------
__device__ void rule2_job(int b, int tid, const float* h1a, const float* w2, const float* b2,
                          const float* emb, float* probs_out, float* sel, float* shf){
  float* lg = shf;
  float* psh = shf + 32;
  int j = tid >> 3, l8 = tid & 7;
  const float* xr = h1a + b * 1024;
  const float* wr = w2 + j * 1024;
  float acc = 0.f;
  #pragma unroll 8
  for (int kk = 0; kk < 32; kk++){
    int k = kk * 32 + l8 * 4;
    float4 xv = *(const float4*)(xr + k);
    float4 wv = *(const float4*)(wr + k);
    acc += xv.x * wv.x + xv.y * wv.y + xv.z * wv.z + xv.w * wv.w;
  }
  acc += __shfl_xor(acc, 1); acc += __shfl_xor(acc, 2); acc += __shfl_xor(acc, 4);
  if (l8 == 0) lg[j] = acc + b2[j];
  __syncthreads();
  if (tid < 32){
    float v = lg[tid];
    float m = v;
    for (int o = 1; o < 32; o <<= 1) m = fmaxf(m, __shfl_xor(m, o));
    float e = __expf(v - m);
    float s = e;
    for (int o = 1; o < 32; o <<= 1) s += __shfl_xor(s, o);
    float p = e / s;
    psh[tid] = p;
    probs_out[b * 32 + tid] = p;
  }
  __syncthreads();
  for (int j2 = tid; j2 < 1024; j2 += 256){
    float a2 = 0.f;
    #pragma unroll
    for (int r = 0; r < 32; r++) a2 += psh[r] * emb[r * 1024 + j2];
    sel[b * 1024 + j2] = a2;
  }
}

// ---------------- A': rule(64) | q(64) | lstm0(256) | psOut(64, t>=1) ----------------
__global__ __launch_bounds__(256) void step_d1_k(LinSeg sRule, LinSeg sQ, LinSeg sL0, LinSeg sPs){
  __shared__ float red[4][32][16];
  int bx = blockIdx.x, tid = threadIdx.x;
  if (bx < 64){ lin_body(sRule, bx, tid, red); return; }
  if (bx < 128){ lin_body(sQ, bx - 64, tid, red); return; }
  if (bx < 384){ lin_body(sL0, bx - 128, tid, red); return; }
  lin_body(sPs, bx - 384, tid, red);
}

// ---------------- B: attention(512) | rule2(32) | lstm1(256) | LN-zero(1) ----------------
struct D2Params {
  const float* qbuf;
  const u16* Kt; const u16* Vb; float* afull; float* ctx0;
  const float* h1a; const float* w2; const float* b2r; const float* emb;
  float* probs_out; float* sel;
  LinSeg sL1; float* lnstats;
};
__global__ __launch_bounds__(256) void step_d2_k(D2Params P){
  __shared__ float red[4][32][16];
  float* shf = &red[0][0][0];
  int bx = blockIdx.x, tid = threadIdx.x;
  if (bx < 512){ attn_job(bx, tid, P.qbuf, P.Kt, P.Vb, P.afull, P.ctx0, shf); return; }
  if (bx < 544){ rule2_job(bx - 512, tid, P.h1a, P.w2, P.b2r, P.emb, P.probs_out, P.sel, shf); return; }
  if (bx < 800){ lin_body(P.sL1, bx - 544, tid, red); return; }
  if (tid < 64) P.lnstats[tid] = 0.f;
}

// ---------------- batched value head + verifier, grid (64, 17) ----------------
__global__ __launch_bounds__(256) void valver_k(const u16* __restrict__ vw1, const float* __restrict__ vb1,
    const u16* __restrict__ verw1, const float* __restrict__ verb1,
    const float* __restrict__ proof, float* __restrict__ v1){
  __shared__ float red[4][32][16];
  int t = blockIdx.y;
  LinSeg S = {};
  if (t < 16){
    S.X0 = proof + (size_t)t * 32768; S.K1 = 1024; S.ldx = 1024; S.W1 = vw1; S.ld1 = 2048; S.b1 = vb1;
    S.Y = proof + (size_t)(t + 1) * 32768; S.K2 = 1024; S.W2 = vw1 + 1024; S.ld2 = 2048;
  } else {
    S.X0 = proof + (size_t)16 * 32768; S.K1 = 1024; S.ldx = 1024; S.W1 = verw1; S.ld1 = 1024; S.b1 = verb1;
  }
  S.out = v1 + (size_t)t * 32768; S.N = 1024; S.act = 1;
  lin_body(S, blockIdx.x, threadIdx.x, red);
}

__global__ __launch_bounds__(256) void dotsig_b_k(const float* __restrict__ v1,
    const float* __restrict__ w2v, const float* __restrict__ b2v,
    const float* __restrict__ w2ver, const float* __restrict__ b2ver,
    float* __restrict__ out_vals, float* __restrict__ out_valid){
  int t = blockIdx.x;
  const float* w = (t < 16) ? w2v : w2ver;
  const float* bs = (t < 16) ? b2v : b2ver;
  const float* x = v1 + (size_t)t * 32768;
  int b = threadIdx.x >> 3, l8 = threadIdx.x & 7;
  const float* xr = x + (size_t)b * 1024;
  float acc = 0.f;
  #pragma unroll 8
  for (int kk = 0; kk < 32; kk++){
    int k = kk * 32 + l8 * 4;
    float4 xv = *(const float4*)(xr + k);
    float4 wv = *(const float4*)(w + k);
    acc += xv.x * wv.x + xv.y * wv.y + xv.z * wv.z + xv.w * wv.w;
  }
  acc += __shfl_xor(acc, 1); acc += __shfl_xor(acc, 2); acc += __shfl_xor(acc, 4);
  if (l8 == 0){
    float r = sigm_f(acc + bs[0]);
    if (t < 16) out_vals[t * 32 + b] = r; else out_valid[b] = r;
  }
}

// ---------------- batched attn head-mean ----------------
__global__ __launch_bounds__(256) void attnavg_all_k(const float* __restrict__ afull, float* __restrict__ out){
  int idx = blockIdx.x * 256 + threadIdx.x;     // 16*32768
  int t = idx >> 15, r = idx & 32767;
  int b = r >> 10, s = r & 1023;
  const float* base = afull + (size_t)t * 524288 + (size_t)b * 16384;
  float acc = 0.f;
  #pragma unroll
  for (int h = 0; h < 16; h++) acc += base[h * 1024 + s];
  out[idx] = acc * (1.f / 16.f);
}

extern "C" void kernel_launch(void* const* d_in, const int* in_sizes, int n_in,
                              void* d_out, int out_size, void* d_ws, size_t ws_size,
                              hipStream_t stream) {
  const float* comp      = (const float*)d_in[0];
  const float* rule_w1   = (const float*)d_in[2];
  const float* rule_b1   = (const float*)d_in[3];
  const float* rule_w2   = (const float*)d_in[4];
  const float* rule_b2   = (const float*)d_in[5];
  const float* rule_emb  = (const float*)d_in[6];
  const float* attn_in_w = (const float*)d_in[7];
  const float* attn_in_b = (const float*)d_in[8];
  const float* attn_out_w= (const float*)d_in[9];
  const float* attn_out_b= (const float*)d_in[10];
  const float* wih0 = (const float*)d_in[11];
  const float* whh0 = (const float*)d_in[12];
  const float* bih0 = (const float*)d_in[13];
  const float* bhh0 = (const float*)d_in[14];
  const float* wih1 = (const float*)d_in[15];
  const float* whh1 = (const float*)d_in[16];
  const float* bih1 = (const float*)d_in[17];
  const float* bhh1 = (const float*)d_in[18];
  const float* gen_w1 = (const float*)d_in[19];
  const float* gen_b1 = (const float*)d_in[20];
  const float* ln_g   = (const float*)d_in[21];
  const float* ln_b   = (const float*)d_in[22];
  const float* gen_w2 = (const float*)d_in[23];
  const float* gen_b2 = (const float*)d_in[24];
  const float* val_w1 = (const float*)d_in[25];
  const float* val_b1 = (const float*)d_in[26];
  const float* val_w2 = (const float*)d_in[27];
  const float* val_b2 = (const float*)d_in[28];
  const float* ver_w1 = (const float*)d_in[29];
  const float* ver_b1 = (const float*)d_in[30];
  const float* ver_w2 = (const float*)d_in[31];
  const float* ver_b2 = (const float*)d_in[32];

  float* out_f     = (float*)d_out;
  float* out_proof = out_f;                       // (17,32,1024)
  float* out_valid = out_f + 17 * 32768;          // (32,1)
  float* out_probs = out_valid + 32;              // (16,32,32)
  float* out_vals  = out_probs + 16 * 1024;       // (16,32,1)
  float* out_attn  = out_vals + 16 * 32;          // (16,32,1024)

  char* wp = (char*)d_ws;
  auto carve = [&](size_t bytes) -> void* {
    void* p = (void*)wp; wp += (bytes + 255) & ~(size_t)255; return p;
  };
  u16* Kt    = (u16*)carve((size_t)33554432 * 2);   // bf16 [b][hd][s]
  u16* Vb    = (u16*)carve((size_t)33554432 * 2);   // bf16 [b][h][s][d]
  u16* compb = (u16*)carve((size_t)33554432 * 2);   // bf16 comp; low 32MB -> afull, high 32MB -> folded wts
  float* afull_all = (float*)compb;                 // 16*512*1024 f32 = 32MB
  char* chi  = (char*)compb + 33554432;             // high half (32MB), free after gemmkv
  u16* gw2T  = (u16*)chi;                           // [2048,1024] bf16, 4MB
  u16* rwg   = (u16*)(chi + 4194304);               // rw1@gw2 [1024,2048], 4MB
  u16* wqg   = (u16*)(chi + 8388608);               // wq@gw2  [1024,2048], 4MB
  u16* wih0g = (u16*)(chi + 12582912);              // wih0@gw2 [4096,2048], 16MB
  u16* rw1b  = (u16*)carve(2097152);
  u16* wqb   = (u16*)carve(2097152);
  u16* wkb   = (u16*)carve(2097152);
  u16* wvb   = (u16*)carve(2097152);
  u16* aowTb = (u16*)carve(2097152);
  u16* wih0b = (u16*)carve(8388608);
  u16* whh0b = (u16*)carve(8388608);
  u16* wih1b = (u16*)carve(8388608);
  u16* whh1b = (u16*)carve(8388608);
  u16* gw1b  = (u16*)carve(4194304);
  u16* gw2b  = (u16*)carve(4194304);
  u16* vw1b  = (u16*)carve(4194304);
  u16* verw1b= (u16*)carve(2097152);
  u16* gaw   = (u16*)carve(4194304);                // gw1@aow [2048,1024]
  u16* g1g   = (u16*)carve(8388608);                // gw1@gw2 [2048,2048]
  float* brl   = (float*)carve(4096);
  float* bqg   = (float*)carve(4096);
  float* bih0g = (float*)carve(16384);
  float* b2t0  = (float*)carve(8192);
  float* b2tn  = (float*)carve(8192);
  float* ps0   = (float*)carve(131072);
  float* h0b[2] = { (float*)carve(131072), (float*)carve(131072) };
  float* c0b[2] = { (float*)carve(131072), (float*)carve(131072) };
  float* h1b[2] = { (float*)carve(131072), (float*)carve(131072) };
  float* c1b[2] = { (float*)carve(131072), (float*)carve(131072) };
  float* zb[2]  = { (float*)carve(262144), (float*)carve(262144) };
  float* lnst[2]= { (float*)carve(256), (float*)carve(256) };
  float* h1act = (float*)carve(131072);
  float* sel   = (float*)carve(131072);
  float* qbuf  = (float*)carve(131072);
  float* ctx0  = (float*)carve(131072);
  float* v1buf = (float*)carve(2228224);
  (void)ws_size; (void)in_sizes; (void)n_in; (void)out_size;

  // ---- casts ----
  CastJobs J;
  const float* srcs[13] = { rule_w1, attn_in_w, attn_in_w + 1048576, attn_in_w + 2097152,
                            wih0, whh0, wih1, whh1, gen_w1, gen_w2, val_w1, ver_w1, comp };
  u16* dsts[13] = { rw1b, wqb, wkb, wvb, wih0b, whh0b, wih1b, whh1b, gw1b, gw2b, vw1b, verw1b, compb };
  int sizes[13] = { 1048576, 1048576, 1048576, 1048576,
                    4194304, 4194304, 4194304, 4194304, 2097152, 2097152, 2097152, 1048576, 33554432 };
  int st = 0;
  for (int i = 0; i < 13; i++){ J.s[i] = srcs[i]; J.d[i] = dsts[i]; J.start[i] = st; st += sizes[i] / 1024; }
  J.start[13] = st;
  cast_all_k<<<dim3(st), dim3(256), 0, stream>>>(J);
  tcast_k<<<dim3(1024), dim3(256), 0, stream>>>(attn_out_w, aowTb);

  gemmkv_k<<<dim3(2048, 1, 2), dim3(256), 0, stream>>>(compb, wkb, wvb,
      attn_in_b + 1024, attn_in_b + 2048, Kt, Vb);

  // gw2T overwrites compb high half (safe after gemmkv consumed compb)
  ttcast_k<<<dim3(2048), dim3(256), 0, stream>>>(gen_w2, gw2T);
  GJobs G;
  G.A[0]=rw1b;  G.B[0]=gw2T;  G.C[0]=rwg;   G.mb[0]=8;  G.nb[0]=16; G.ldc[0]=2048;
  G.A[1]=wqb;   G.B[1]=gw2T;  G.C[1]=wqg;   G.mb[1]=8;  G.nb[1]=16; G.ldc[1]=2048;
  G.A[2]=wih0b; G.B[2]=gw2T;  G.C[2]=wih0g; G.mb[2]=32; G.nb[2]=16; G.ldc[2]=2048;
  G.A[3]=gw1b;  G.B[3]=gw2T;  G.C[3]=g1g;   G.mb[3]=16; G.nb[3]=16; G.ldc[3]=2048;
  G.A[4]=gw1b;  G.B[4]=aowTb; G.C[4]=gaw;   G.mb[4]=16; G.nb[4]=8;  G.ldc[4]=1024;
  gemmbb_k<<<dim3(32, 16, 5), dim3(256), 0, stream>>>(G);

  BJobs B;
  B.W[0]=rule_w1;  B.v[0]=gen_b2;     B.v2[0]=nullptr; B.base[0]=rule_b1;   B.out[0]=brl;
  B.W[1]=attn_in_w;B.v[1]=gen_b2;     B.v2[1]=nullptr; B.base[1]=attn_in_b; B.out[1]=bqg;
  B.W[2]=wih0;     B.v[2]=gen_b2;     B.v2[2]=nullptr; B.base[2]=bih0;      B.out[2]=bih0g;
  B.W[3]=gen_w1;   B.v[3]=attn_out_b; B.v2[3]=nullptr; B.base[3]=gen_b1;    B.out[3]=b2t0;
  B.W[4]=gen_w1;   B.v[4]=attn_out_b; B.v2[4]=gen_b2;  B.base[4]=gen_b1;    B.out[4]=b2tn;
  B.start[0]=0; B.start[1]=32; B.start[2]=64; B.start[3]=192; B.start[4]=256; B.start[5]=320;
  biasfold_k<<<dim3(320), dim3(256), 0, stream>>>(B);

  init_k<<<dim3(128), dim3(256), 0, stream>>>(comp, ps0, out_proof,
      h0b[0], c0b[0], h1b[0], c1b[0]);

  for (int t = 0; t < 16; t++){
    int cur = t & 1, nx = cur ^ 1;
    int p = nx;                                  // z/lnstats buffer written at t-1
    float* afull_t = afull_all + (size_t)t * 524288;
    // ---- A': rule + q + LSTM0 (+ psOut for t>=1) ----
    LinSeg sRule = {}, sQ = {}, sL0 = {}, sPs = {};
    if (t == 0){
      sRule.X0 = ps0; sRule.K1 = 1024; sRule.ldx = 1024; sRule.W1 = rw1b; sRule.ld1 = 1024;
      sRule.b1 = rule_b1;
      sQ.X0 = ps0; sQ.K1 = 1024; sQ.ldx = 1024; sQ.W1 = wqb; sQ.ld1 = 1024; sQ.b1 = attn_in_b;
      sL0.X0 = ps0; sL0.K1 = 1024; sL0.ldx = 1024; sL0.W1 = wih0b; sL0.ld1 = 1024; sL0.b1 = bih0;
    } else {
      sRule.Zp = zb[p]; sRule.KZ = 2048; sRule.ldz = 2048; sRule.WZ = rwg; sRule.ldwz = 2048;
      sRule.lng = ln_g; sRule.lnb = ln_b; sRule.lnstats = lnst[p]; sRule.b1 = brl;
      sQ.Zp = zb[p]; sQ.KZ = 2048; sQ.ldz = 2048; sQ.WZ = wqg; sQ.ldwz = 2048;
      sQ.lng = ln_g; sQ.lnb = ln_b; sQ.lnstats = lnst[p]; sQ.b1 = bqg;
      sL0.Zp = zb[p]; sL0.KZ = 2048; sL0.ldz = 2048; sL0.WZ = wih0g; sL0.ldwz = 2048;
      sL0.lng = ln_g; sL0.lnb = ln_b; sL0.lnstats = lnst[p]; sL0.b1 = bih0g;
      sPs.Zp = zb[p]; sPs.KZ = 2048; sPs.ldz = 2048; sPs.WZ = gw2b; sPs.ldwz = 2048;
      sPs.lng = ln_g; sPs.lnb = ln_b; sPs.lnstats = lnst[p]; sPs.b1 = gen_b2;
      sPs.out = out_proof + (size_t)t * 32768; sPs.N = 1024;
    }
    sRule.out = h1act; sRule.N = 1024; sRule.act = 1;
    sQ.out = qbuf; sQ.N = 1024; sQ.act = 2; sQ.scale = 0.125f;
    sL0.Y = h0b[cur]; sL0.K2 = 1024; sL0.W2 = whh0b; sL0.ld2 = 1024; sL0.b2 = bhh0;
    sL0.gate = 1; sL0.cprev = c0b[cur]; sL0.cout = c0b[nx]; sL0.hout = h0b[nx];
    step_d1_k<<<dim3(t ? 448 : 384), dim3(256), 0, stream>>>(sRule, sQ, sL0, sPs);
    // ---- B: attention + rule2 + LSTM1 + zero lnst[cur] ----
    D2Params P;
    P.qbuf = qbuf; P.Kt = Kt; P.Vb = Vb; P.afull = afull_t; P.ctx0 = ctx0;
    P.h1a = h1act; P.w2 = rule_w2; P.b2r = rule_b2; P.emb = rule_emb;
    P.probs_out = out_probs + t * 1024; P.sel = sel;
    LinSeg sL1 = {}; sL1.X0 = h0b[nx]; sL1.K1 = 1024; sL1.ldx = 1024;
    sL1.W1 = wih1b; sL1.ld1 = 1024; sL1.b1 = bih1;
    sL1.Y = h1b[cur]; sL1.K2 = 1024; sL1.W2 = whh1b; sL1.ld2 = 1024; sL1.b2 = bhh1;
    sL1.gate = 1; sL1.cprev = c1b[cur]; sL1.cout = c1b[nx]; sL1.hout = h1b[nx];
    P.sL1 = sL1; P.lnstats = lnst[cur];
    step_d2_k<<<dim3(801), dim3(256), 0, stream>>>(P);
    // ---- C: z = (sel+mem[+ps0])@gw1^T + ctx@gaw^T [+ phi(z_prev)@g1g^T] + bias ----
    LinSeg sG = {};
    if (t == 0){
      sG.X0 = ps0; sG.Xa = sel; sG.Xb = h1b[nx]; sG.b1 = b2t0;
    } else {
      sG.X0 = sel; sG.Xa = h1b[nx]; sG.b1 = b2tn;
      sG.Zp = zb[p]; sG.KZ = 2048; sG.ldz = 2048; sG.WZ = g1g; sG.ldwz = 2048;
      sG.lng = ln_g; sG.lnb = ln_b; sG.lnstats = lnst[p];
    }
    sG.K1 = 1024; sG.ldx = 1024; sG.W1 = gw1b; sG.ld1 = 1024;
    sG.Y = ctx0; sG.K2 = 1024; sG.W2 = gaw; sG.ld2 = 1024;
    sG.out = zb[cur]; sG.N = 2048; sG.stats = lnst[cur];
    linmulti_k<<<dim3(128), dim3(256), 0, stream>>>(sG, sG, sG, 128, 0);
  }
  // ---- post-loop: ps_16, value heads + verifier, attn head-mean ----
  LinSeg sFin = {};
  sFin.Zp = zb[1]; sFin.KZ = 2048; sFin.ldz = 2048; sFin.WZ = gw2b; sFin.ldwz = 2048;
  sFin.lng = ln_g; sFin.lnb = ln_b; sFin.lnstats = lnst[1]; sFin.b1 = gen_b2;
  sFin.out = out_proof + (size_t)16 * 32768; sFin.N = 1024;
  linmulti_k<<<dim3(64), dim3(256), 0, stream>>>(sFin, sFin, sFin, 64, 0);
  valver_k<<<dim3(64, 17), dim3(256), 0, stream>>>(vw1b, val_b1, verw1b, ver_b1, out_proof, v1buf);
  dotsig_b_k<<<dim3(17), dim3(256), 0, stream>>>(v1buf, val_w2, val_b2, ver_w2, ver_b2,
      out_vals, out_valid);
  attnavg_all_k<<<dim3(2048), dim3(256), 0, stream>>>(afull_all, out_attn);
}

// Round 12
// 2099.781 us; speedup vs baseline: 1.1617x; 1.1617x over previous
//
#include <hip/hip_runtime.h>

typedef unsigned short u16;
typedef unsigned int u32;
typedef __attribute__((ext_vector_type(8))) short short8v;   // 8 bf16 (4 VGPRs)
typedef __attribute__((ext_vector_type(4))) float f32x4;

#define MFMA16(a,b,c) __builtin_amdgcn_mfma_f32_16x16x32_bf16((a),(b),(c),0,0,0)

__device__ __forceinline__ u16 f2bf(float f){
  u32 u = __float_as_uint(f);
  return (u16)((u + 0x7fffu + ((u >> 16) & 1u)) >> 16);   // RNE
}
__device__ __forceinline__ float bf2f(u16 h){ return __uint_as_float(((u32)h) << 16); }
__device__ __forceinline__ float gelu_f(float x){ return 0.5f * x * (1.f + erff(x * 0.70710678118654752f)); }
__device__ __forceinline__ float sigm_f(float x){ return 1.f / (1.f + __expf(-x)); }
__device__ __forceinline__ void acc4(float4& a, const float4 b){ a.x+=b.x; a.y+=b.y; a.z+=b.z; a.w+=b.w; }

// async global->LDS, 16B per lane
__device__ __forceinline__ void gl16(const void* g, void* l){
  __builtin_amdgcn_global_load_lds((const __attribute__((address_space(1))) u32*)g,
                                   (__attribute__((address_space(3))) u32*)l, 16, 0, 0);
}

// ---------------- fused cast fp32 -> bf16 (13 jobs incl comp, one launch) ----------------
struct CastJobs { const float* s[13]; u16* d[13]; int start[14]; };
__global__ __launch_bounds__(256) void cast_all_k(CastJobs J){
  int bx = blockIdx.x, j = 0;
  #pragma unroll
  for (int t = 0; t < 13; t++) if (bx >= J.start[t + 1]) j = t + 1;
  int i = (bx - J.start[j]) * 1024 + threadIdx.x * 4;
  float4 v = *(const float4*)(J.s[j] + i);
  ushort4 o; o.x = f2bf(v.x); o.y = f2bf(v.y); o.z = f2bf(v.z); o.w = f2bf(v.w);
  *(ushort4*)(J.d[j] + i) = o;
}

// ---------------- transpose-cast 1024x1024 fp32 -> bf16^T ----------------
__global__ __launch_bounds__(256) void tcast_k(const float* __restrict__ s, u16* __restrict__ d){
  __shared__ float tile[32][33];
  int bx = blockIdx.x & 31, by = blockIdx.x >> 5;
  int tx = threadIdx.x & 31, ty = threadIdx.x >> 5;
  #pragma unroll
  for (int i = 0; i < 4; i++)
    tile[ty + i * 8][tx] = s[(size_t)(by * 32 + ty + i * 8) * 1024 + bx * 32 + tx];
  __syncthreads();
  #pragma unroll
  for (int i = 0; i < 4; i++)
    d[(size_t)(bx * 32 + ty + i * 8) * 1024 + by * 32 + tx] = f2bf(tile[tx][ty + i * 8]);
}

// ---------------- bias2 = gen_b1 + gw1 @ aob ----------------
__global__ __launch_bounds__(256) void bias2_k(const float* __restrict__ gw1, const float* __restrict__ aob,
                                               const float* __restrict__ gb1, float* __restrict__ out){
  int j = blockIdx.x * 32 + (threadIdx.x >> 3);
  int l8 = threadIdx.x & 7;
  const float* r = gw1 + (size_t)j * 1024;
  float acc = 0.f;
  #pragma unroll 8
  for (int kk = 0; kk < 32; kk++){
    int k = kk * 32 + l8 * 4;
    float4 a = *(const float4*)(r + k);
    float4 w = *(const float4*)(aob + k);
    acc += a.x * w.x + a.y * w.y + a.z * w.z + a.w * w.w;
  }
  acc += __shfl_xor(acc, 1); acc += __shfl_xor(acc, 2); acc += __shfl_xor(acc, 4);
  if (l8 == 0) out[j] = gb1[j] + acc;
}

// ---------------- init: ps partials, zero states ----------------
__global__ __launch_bounds__(256) void init_k(const float* __restrict__ comp, float* psa, float* psbz,
                                              float* outp, float* h0, float* c0, float* h1, float* c1){
  int i = blockIdx.x * 256 + threadIdx.x;       // 32768
  int b = i >> 10, hh = i & 1023;
  float v = comp[(size_t)b * 1048576 + hh];
  psa[i] = v; psbz[i] = 0.f; outp[i] = v;
  h0[i] = 0.f; c0[i] = 0.f; h1[i] = 0.f; c1[i] = 0.f;
}

// ---------------- fused K/V GEMM (bf16 out). Kt:[b][hd][s], Vb:[b][h][s][d] ----------------
__global__ __launch_bounds__(256) void gemmkv_k(const u16* __restrict__ compb,
    const u16* __restrict__ Wk, const u16* __restrict__ Wv,
    const float* __restrict__ bk, const float* __restrict__ bv,
    u16* __restrict__ Kt, u16* __restrict__ Vb)
{
  __shared__ u16 Sh[16384];               // As(16KB)+Bs(16KB); reused as C-tile
  u16* As = Sh;
  u16* Bs = Sh + 8192;
  int tid = threadIdx.x;
  int x = blockIdx.x;
  int xcd = x & 7, p = x >> 3;
  int cpanel = xcd * 32 + (p >> 3);
  int wpanel = p & 7;
  int isK = (blockIdx.z != 0);
  const u16 *msrc, *nsrc; int m0, n0;
  if (!isK){ m0 = cpanel * 128; n0 = wpanel * 128; msrc = compb; nsrc = Wv; }
  else     { m0 = wpanel * 128; n0 = cpanel * 128; msrc = Wk;    nsrc = compb; }

  int w = tid >> 6, l = tid & 63, lr = l & 15, lk = l >> 4;
  int wm = (w >> 1) * 64, wn = (w & 1) * 64;
  f32x4 acc[4][4];
  #pragma unroll
  for (int i = 0; i < 4; i++)
    #pragma unroll
    for (int j = 0; j < 4; j++) acc[i][j] = (f32x4){0.f,0.f,0.f,0.f};

  for (int kc = 0; kc < 1024; kc += 64){
    #pragma unroll
    for (int r = 0; r < 4; r++){
      int s = tid + r * 256;
      int row = s >> 3, pp = s & 7;
      int lg = pp ^ (row & 7);
      gl16(msrc + (size_t)(m0 + row) * 1024 + kc + lg * 8, As + s * 8);
      gl16(nsrc + (size_t)(n0 + row) * 1024 + kc + lg * 8, Bs + s * 8);
    }
    __syncthreads();
    #pragma unroll
    for (int kk = 0; kk < 2; kk++){
      short8v a[4], bb[4];
      #pragma unroll
      for (int mi = 0; mi < 4; mi++){
        int row = wm + mi * 16 + lr;
        int ph = (kk * 4 + lk) ^ (row & 7);
        a[mi] = *(const short8v*)(As + row * 64 + ph * 8);
      }
      #pragma unroll
      for (int ni = 0; ni < 4; ni++){
        int row = wn + ni * 16 + lr;
        int ph = (kk * 4 + lk) ^ (row & 7);
        bb[ni] = *(const short8v*)(Bs + row * 64 + ph * 8);
      }
      #pragma unroll
      for (int mi = 0; mi < 4; mi++)
        #pragma unroll
        for (int ni = 0; ni < 4; ni++)
          acc[mi][ni] = MFMA16(a[mi], bb[ni], acc[mi][ni]);
    }
    __syncthreads();
  }
  #pragma unroll
  for (int mi = 0; mi < 4; mi++)
    #pragma unroll
    for (int ni = 0; ni < 4; ni++)
      #pragma unroll
      for (int r = 0; r < 4; r++){
        int row = wm + mi * 16 + lk * 4 + r;
        int col = wn + ni * 16 + lr;
        float bias = isK ? bk[m0 + row] : bv[n0 + col];
        Sh[row * 128 + col] = f2bf(acc[mi][ni][r] + bias);
      }
  __syncthreads();
  for (int i = tid; i < 2048; i += 256){
    int r = i >> 4, c8 = (i & 15) * 8;
    uint4 o = *(const uint4*)(Sh + r * 128 + c8);
    if (!isK){
      int bs = m0 + r, hd = n0 + c8;
      int b = bs >> 10, s = bs & 1023;
      int h = hd >> 6, d = hd & 63;
      *(uint4*)(Vb + ((size_t)(b * 16 + h) * 1024 + s) * 64 + d) = o;
    } else {
      int hd = m0 + r, bs = n0 + c8;
      int b = bs >> 10, s = bs & 1023;
      *(uint4*)(Kt + ((size_t)b * 1024 + hd) * 1024 + s) = o;
    }
  }
}

// ---------------- gaw = gw1 @ aow ----------------
__global__ __launch_bounds__(256) void gemmbb_k(const u16* __restrict__ A, const u16* __restrict__ B,
                                                u16* __restrict__ C)
{
  __shared__ u16 As[128 * 64];
  __shared__ u16 Bs[128 * 64];
  int tid = threadIdx.x;
  int m0 = blockIdx.x * 128, n0 = blockIdx.y * 128;
  int w = tid >> 6, l = tid & 63, lr = l & 15, lk = l >> 4;
  int wm = (w >> 1) * 64, wn = (w & 1) * 64;
  f32x4 acc[4][4];
  #pragma unroll
  for (int i = 0; i < 4; i++)
    #pragma unroll
    for (int j = 0; j < 4; j++) acc[i][j] = (f32x4){0.f,0.f,0.f,0.f};
  for (int kc = 0; kc < 1024; kc += 64){
    #pragma unroll
    for (int r = 0; r < 4; r++){
      int s = tid + r * 256;
      int row = s >> 3, pp = s & 7;
      int lg = pp ^ (row & 7);
      gl16(A + (size_t)(m0 + row) * 1024 + kc + lg * 8, As + s * 8);
      gl16(B + (size_t)(n0 + row) * 1024 + kc + lg * 8, Bs + s * 8);
    }
    __syncthreads();
    #pragma unroll
    for (int kk = 0; kk < 2; kk++){
      short8v a[4], bb[4];
      #pragma unroll
      for (int mi = 0; mi < 4; mi++){
        int row = wm + mi * 16 + lr;
        int ph = (kk * 4 + lk) ^ (row & 7);
        a[mi] = *(const short8v*)(As + row * 64 + ph * 8);
      }
      #pragma unroll
      for (int ni = 0; ni < 4; ni++){
        int row = wn + ni * 16 + lr;
        int ph = (kk * 4 + lk) ^ (row & 7);
        bb[ni] = *(const short8v*)(Bs + row * 64 + ph * 8);
      }
      #pragma unroll
      for (int mi = 0; mi < 4; mi++)
        #pragma unroll
        for (int ni = 0; ni < 4; ni++)
          acc[mi][ni] = MFMA16(a[mi], bb[ni], acc[mi][ni]);
    }
    __syncthreads();
  }
  #pragma unroll
  for (int mi = 0; mi < 4; mi++)
    #pragma unroll
    for (int ni = 0; ni < 4; ni++)
      #pragma unroll
      for (int r = 0; r < 4; r++){
        int row = m0 + wm + mi * 16 + lk * 4 + r;
        int col = n0 + wn + ni * 16 + lr;
        C[(size_t)row * 1024 + col] = f2bf(acc[mi][ni][r]);
      }
}

// ---------------- M=32, N=16 MFMA linear tile (256 threads / 4 waves, 8KB red) ----------------
struct LinSeg {
  const float* X0; const float* Xa; const float* Xb; const float* Xc;
  const u16* W1; const float* b1;
  const float* Y; const u16* W2; const float* b2;
  float* out; float* out2;
  int K1, ldx, ld1, K2, ld2, N, act, gate;   // ldx: A row stride; act 0/1 gelu/2 scale
  float scale;
  float* stats;
  const float* lng; const float* lnb; const float* lnstats;
  const float* cprev; float* cout; float* hout;
};

__device__ __forceinline__ short8v pack8(float4 v0, float4 v1){
  short8v r;
  r[0]=(short)f2bf(v0.x); r[1]=(short)f2bf(v0.y); r[2]=(short)f2bf(v0.z); r[3]=(short)f2bf(v0.w);
  r[4]=(short)f2bf(v1.x); r[5]=(short)f2bf(v1.y); r[6]=(short)f2bf(v1.z); r[7]=(short)f2bf(v1.w);
  return r;
}

__device__ __forceinline__ short8v load_sum8(const LinSeg& S, int row, int kb){
  size_t o = (size_t)row * S.ldx + kb;
  float4 v0 = *(const float4*)(S.X0 + o);
  float4 v1 = *(const float4*)(S.X0 + o + 4);
  if (S.lng){
    float mu = S.lnstats[row] * (1.f / 2048.f);
    float ms = S.lnstats[32 + row] * (1.f / 2048.f);
    float rstd = rsqrtf(ms - mu * mu + 1e-5f);
    float4 g0 = *(const float4*)(S.lng + kb), g1 = *(const float4*)(S.lng + kb + 4);
    float4 b0 = *(const float4*)(S.lnb + kb), b1 = *(const float4*)(S.lnb + kb + 4);
    v0.x = gelu_f((v0.x - mu) * rstd * g0.x + b0.x);
    v0.y = gelu_f((v0.y - mu) * rstd * g0.y + b0.y);
    v0.z = gelu_f((v0.z - mu) * rstd * g0.z + b0.z);
    v0.w = gelu_f((v0.w - mu) * rstd * g0.w + b0.w);
    v1.x = gelu_f((v1.x - mu) * rstd * g1.x + b1.x);
    v1.y = gelu_f((v1.y - mu) * rstd * g1.y + b1.y);
    v1.z = gelu_f((v1.z - mu) * rstd * g1.z + b1.z);
    v1.w = gelu_f((v1.w - mu) * rstd * g1.w + b1.w);
  } else {
    if (S.Xa){ acc4(v0, *(const float4*)(S.Xa + o)); acc4(v1, *(const float4*)(S.Xa + o + 4)); }
    if (S.Xb){ acc4(v0, *(const float4*)(S.Xb + o)); acc4(v1, *(const float4*)(S.Xb + o + 4)); }
    if (S.Xc){ acc4(v0, *(const float4*)(S.Xc + o)); acc4(v1, *(const float4*)(S.Xc + o + 4)); }
  }
  return pack8(v0, v1);
}
__device__ __forceinline__ short8v load_y8(const float* p){
  return pack8(*(const float4*)(p), *(const float4*)(p + 4));
}

typedef float Red16[32][16];   // red[4][32][16] = 8KB

__device__ void lin_body(const LinSeg& S, int bi, int tid, Red16* red){
  int c0 = bi * 16, j0 = bi * 4;
  int w = tid >> 6, l = tid & 63, lr = l & 15, lk = l >> 4;
  int wc0 = S.gate ? ((lr >> 2) << 10) + j0 + (lr & 3) : c0 + lr;
  f32x4 acc[2];
  acc[0] = (f32x4){0.f,0.f,0.f,0.f};
  acc[1] = (f32x4){0.f,0.f,0.f,0.f};

  {
    int chunk = S.K1 >> 2;
    int kb0 = w * chunk + lk * 8;
    for (int kk = 0; kk < chunk; kk += 32){
      int kb = kb0 + kk;
      short8v a0 = load_sum8(S, lr, kb);
      short8v a1 = load_sum8(S, lr + 16, kb);
      short8v w0 = *(const short8v*)(S.W1 + (size_t)wc0 * S.ld1 + kb);
      acc[0] = MFMA16(a0, w0, acc[0]);
      acc[1] = MFMA16(a1, w0, acc[1]);
    }
  }
  if (S.Y){
    int chunk = S.K2 >> 2;
    int kb0 = w * chunk + lk * 8;
    for (int kk = 0; kk < chunk; kk += 32){
      int kb = kb0 + kk;
      short8v a0 = load_y8(S.Y + (size_t)lr * S.K2 + kb);
      short8v a1 = load_y8(S.Y + (size_t)(lr + 16) * S.K2 + kb);
      short8v w0 = *(const short8v*)(S.W2 + (size_t)wc0 * S.ld2 + kb);
      acc[0] = MFMA16(a0, w0, acc[0]);
      acc[1] = MFMA16(a1, w0, acc[1]);
    }
  }
  #pragma unroll
  for (int mi = 0; mi < 2; mi++)
    #pragma unroll
    for (int r = 0; r < 4; r++)
      red[w][mi * 16 + lk * 4 + r][lr] = acc[mi][r];
  __syncthreads();
  if (S.gate){
    if (tid < 128){
      int row = tid >> 2, j = tid & 3;
      float s[4];
      #pragma unroll
      for (int g = 0; g < 4; g++){
        float v = 0.f;
        #pragma unroll
        for (int ww = 0; ww < 4; ww++) v += red[ww][row][g * 4 + j];
        s[g] = v;
      }
      int gc = j0 + j;
      float gI = s[0] + S.b1[gc]        + S.b2[gc];
      float gF = s[1] + S.b1[1024 + gc] + S.b2[1024 + gc];
      float gG = s[2] + S.b1[2048 + gc] + S.b2[2048 + gc];
      float gO = s[3] + S.b1[3072 + gc] + S.b2[3072 + gc];
      int idx = row * 1024 + gc;
      float cN = sigm_f(gF) * S.cprev[idx] + sigm_f(gI) * tanhf(gG);
      S.cout[idx] = cN;
      S.hout[idx] = sigm_f(gO) * tanhf(cN);
    }
    return;
  }
  float vout[2]; int iout[2];
  int cnt = 0;
  for (int i = tid; i < 512; i += 256){
    int row = i >> 4, col = i & 15;
    float v = 0.f;
    #pragma unroll
    for (int ww = 0; ww < 4; ww++) v += red[ww][row][col];
    if (S.b1) v += S.b1[c0 + col];
    if (S.b2) v += S.b2[c0 + col];
    if (S.act == 1) v = gelu_f(v);
    else if (S.act == 2) v *= S.scale;
    S.out[(size_t)row * S.N + c0 + col] = v;
    if (S.out2) S.out2[(size_t)row * S.N + c0 + col] = v;
    vout[cnt] = v; iout[cnt] = i; cnt++;
  }
  if (S.stats){
    __syncthreads();
    float* rf = (float*)red;
    rf[iout[0]] = vout[0]; rf[512 + iout[0]] = vout[0] * vout[0];
    rf[iout[1]] = vout[1]; rf[512 + iout[1]] = vout[1] * vout[1];
    __syncthreads();
    if (tid < 32){
      float s = 0.f, s2 = 0.f;
      #pragma unroll
      for (int cc = 0; cc < 16; cc++){ s += rf[tid * 16 + cc]; s2 += rf[512 + tid * 16 + cc]; }
      atomicAdd(S.stats + tid, s);
      atomicAdd(S.stats + 32 + tid, s2);
    }
  }
}

__global__ __launch_bounds__(256) void linmulti_k(LinSeg s0, LinSeg s1, LinSeg s2, int n0, int n1){
  __shared__ float red[4][32][16];
  int bx = blockIdx.x, tid = threadIdx.x;
  if (bx < n0) lin_body(s0, bx, tid, red);
  else if (bx < n0 + n1) lin_body(s1, bx - n0, tid, red);
  else lin_body(s2, bx - n0 - n1, tid, red);
}

// ---------------- attention job (256 threads, bf16 K/V, uint2 loads both phases) ----------------
__device__ void attn_job(int bh, int tid, const float* q, const u16* Kt, const u16* Vb,
                         float* afull, float* ctx0, float* shf){
  float* qs = shf;            // 64
  float* sc = shf + 64;       // 1024
  float* rr = shf + 1088;     // 8
  float* ctxp = shf + 1096;   // 16*64 = 1024  (total 2120 <= 2176)
  int b = bh >> 4, h = bh & 15;
  if (tid < 64) qs[tid] = q[bh * 64 + tid];
  __syncthreads();
  // score: thread owns s = 4*tid .. 4*tid+3 (8B loads)
  const uint2* kt2 = (const uint2*)(Kt + (size_t)bh * 65536);   // [d][s] rows of 256 uint2
  float a0 = 0.f, a1 = 0.f, a2 = 0.f, a3 = 0.f;
  #pragma unroll 8
  for (int d = 0; d < 64; d++){
    float qd = qs[d];
    uint2 p = kt2[d * 256 + tid];
    a0 += qd * bf2f((u16)(p.x & 0xffff));
    a1 += qd * bf2f((u16)(p.x >> 16));
    a2 += qd * bf2f((u16)(p.y & 0xffff));
    a3 += qd * bf2f((u16)(p.y >> 16));
  }
  float mx = fmaxf(fmaxf(a0, a1), fmaxf(a2, a3));
  for (int o = 1; o < 64; o <<= 1) mx = fmaxf(mx, __shfl_xor(mx, o));
  if ((tid & 63) == 0) rr[tid >> 6] = mx;
  __syncthreads();
  mx = fmaxf(fmaxf(rr[0], rr[1]), fmaxf(rr[2], rr[3]));
  float e0 = __expf(a0 - mx), e1 = __expf(a1 - mx), e2 = __expf(a2 - mx), e3 = __expf(a3 - mx);
  float sm = e0 + e1 + e2 + e3;
  for (int o = 1; o < 64; o <<= 1) sm += __shfl_xor(sm, o);
  if ((tid & 63) == 0) rr[4 + (tid >> 6)] = sm;
  __syncthreads();
  sm = rr[4] + rr[5] + rr[6] + rr[7];
  float inv = 1.f / sm;
  float4 wv = make_float4(e0 * inv, e1 * inv, e2 * inv, e3 * inv);
  *(float4*)(sc + 4 * tid) = wv;
  *(float4*)(afull + (size_t)bh * 1024 + 4 * tid) = wv;
  __syncthreads();
  // PV: 16 chunks x 64 s; 16 threads/chunk own 4 d each (8B loads)
  int dd = (tid & 15) * 4, chunk = tid >> 4;
  const uint2* vp2 = (const uint2*)(Vb + ((size_t)(b * 16 + h) * 1024 + chunk * 64) * 64 + dd);
  const float* scp = sc + chunk * 64;
  float c0 = 0.f, c1 = 0.f, c2 = 0.f, c3 = 0.f;
  #pragma unroll 8
  for (int s = 0; s < 64; s++){
    uint2 vv = vp2[s * 16];
    float w = scp[s];
    c0 += w * bf2f((u16)(vv.x & 0xffff));
    c1 += w * bf2f((u16)(vv.x >> 16));
    c2 += w * bf2f((u16)(vv.y & 0xffff));
    c3 += w * bf2f((u16)(vv.y >> 16));
  }
  *(float4*)(ctxp + chunk * 64 + dd) = make_float4(c0, c1, c2, c3);
  __syncthreads();
  if (tid < 64){
    float r = 0.f;
    #pragma unroll
    for (int c = 0; c < 16; c++) r += ctxp[c * 64 + tid];
    ctx0[bh * 64 + tid] = r;
  }
}

// ---------------- rule softmax + sel job ----------------
__device__ void rule2_job(int b, int tid, const float* h1a, const float* w2, const float* b2,
                          const float* emb, float* probs_out, float* sel, float* shf){
  float* lg = shf;
  float* psh = shf + 32;
  int j = tid >> 3, l8 = tid & 7;
  const float* xr = h1a + b * 1024;
  const float* wr = w2 + j * 1024;
  float acc = 0.f;
  #pragma unroll 8
  for (int kk = 0; kk < 32; kk++){
    int k = kk * 32 + l8 * 4;
    float4 xv = *(const float4*)(xr + k);
    float4 wv = *(const float4*)(wr + k);
    acc += xv.x * wv.x + xv.y * wv.y + xv.z * wv.z + xv.w * wv.w;
  }
  acc += __shfl_xor(acc, 1); acc += __shfl_xor(acc, 2); acc += __shfl_xor(acc, 4);
  if (l8 == 0) lg[j] = acc + b2[j];
  __syncthreads();
  if (tid < 32){
    float v = lg[tid];
    float m = v;
    for (int o = 1; o < 32; o <<= 1) m = fmaxf(m, __shfl_xor(m, o));
    float e = __expf(v - m);
    float s = e;
    for (int o = 1; o < 32; o <<= 1) s += __shfl_xor(s, o);
    float p = e / s;
    psh[tid] = p;
    probs_out[b * 32 + tid] = p;
  }
  __syncthreads();
  for (int j2 = tid; j2 < 1024; j2 += 256){
    float a2 = 0.f;
    #pragma unroll
    for (int r = 0; r < 32; r++) a2 += psh[r] * emb[r * 1024 + j2];
    sel[b * 1024 + j2] = a2;
  }
}

// ---------------- D1: rule(64) | q(64) | lstm0(256) | proof-fixup(32) ----------------
__global__ __launch_bounds__(256) void step_d1_k(LinSeg sRule, LinSeg sQ, LinSeg sL0,
                                                 const float* pa, const float* pb, float* proof_t){
  __shared__ float red[4][32][16];
  int bx = blockIdx.x, tid = threadIdx.x;
  if (bx < 64){ lin_body(sRule, bx, tid, red); return; }
  if (bx < 128){ lin_body(sQ, bx - 64, tid, red); return; }
  if (bx < 384){ lin_body(sL0, bx - 128, tid, red); return; }
  int i = (bx - 384) * 1024 + tid * 4;
  float4 va = *(const float4*)(pa + i);
  float4 vb = *(const float4*)(pb + i);
  acc4(va, vb);
  *(float4*)(proof_t + i) = va;
}

// ---------------- D2: attention(512) | rule2(32) | lstm1(256) | LN-zero(1) ----------------
struct D2Params {
  const float* qbuf;
  const u16* Kt; const u16* Vb; float* afull; float* ctx0;
  const float* h1a; const float* w2; const float* b2r; const float* emb;
  float* probs_out; float* sel;
  LinSeg sL1; float* lnstats;
};
__global__ __launch_bounds__(256) void step_d2_k(D2Params P){
  __shared__ float shmem[2176];          // 8.5KB: attn needs 2120; lin_body uses first 8KB
  int bx = blockIdx.x, tid = threadIdx.x;
  if (bx < 512){ attn_job(bx, tid, P.qbuf, P.Kt, P.Vb, P.afull, P.ctx0, shmem); return; }
  if (bx < 544){ rule2_job(bx - 512, tid, P.h1a, P.w2, P.b2r, P.emb, P.probs_out, P.sel, shmem); return; }
  if (bx < 800){ lin_body(P.sL1, bx - 544, tid, (Red16*)shmem); return; }
  if (tid < 64) P.lnstats[tid] = 0.f;
}

// ---------------- final proof fixup: proof[16] = pa + pb ----------------
__global__ __launch_bounds__(256) void fixup_k(const float* __restrict__ pa, const float* __restrict__ pb,
                                               float* __restrict__ out){
  int i = blockIdx.x * 1024 + threadIdx.x * 4;
  float4 va = *(const float4*)(pa + i);
  float4 vb = *(const float4*)(pb + i);
  acc4(va, vb);
  *(float4*)(out + i) = va;
}

// ---------------- batched value head (16 steps) + verifier, grid (64, 17) ----------------
__global__ __launch_bounds__(256) void valver_k(const u16* __restrict__ vw1, const float* __restrict__ vb1,
    const u16* __restrict__ verw1, const float* __restrict__ verb1,
    const float* __restrict__ proof, const float* __restrict__ pfa, const float* __restrict__ pfb,
    float* __restrict__ v1){
  __shared__ float red[4][32][16];
  int t = blockIdx.y;
  LinSeg S = {};
  if (t < 16){
    S.X0 = proof + (size_t)t * 32768; S.K1 = 1024; S.ldx = 1024; S.W1 = vw1; S.ld1 = 2048; S.b1 = vb1;
    S.Y = proof + (size_t)(t + 1) * 32768; S.K2 = 1024; S.W2 = vw1 + 1024; S.ld2 = 2048;
  } else {
    S.X0 = pfa; S.Xa = pfb; S.K1 = 1024; S.ldx = 1024; S.W1 = verw1; S.ld1 = 1024; S.b1 = verb1;
  }
  S.out = v1 + (size_t)t * 32768; S.N = 1024; S.act = 1;
  lin_body(S, blockIdx.x, threadIdx.x, red);
}

__global__ __launch_bounds__(256) void dotsig_b_k(const float* __restrict__ v1,
    const float* __restrict__ w2v, const float* __restrict__ b2v,
    const float* __restrict__ w2ver, const float* __restrict__ b2ver,
    float* __restrict__ out_vals, float* __restrict__ out_valid){
  int t = blockIdx.x;
  const float* w = (t < 16) ? w2v : w2ver;
  const float* bs = (t < 16) ? b2v : b2ver;
  const float* x = v1 + (size_t)t * 32768;
  int b = threadIdx.x >> 3, l8 = threadIdx.x & 7;
  const float* xr = x + (size_t)b * 1024;
  float acc = 0.f;
  #pragma unroll 8
  for (int kk = 0; kk < 32; kk++){
    int k = kk * 32 + l8 * 4;
    float4 xv = *(const float4*)(xr + k);
    float4 wv = *(const float4*)(w + k);
    acc += xv.x * wv.x + xv.y * wv.y + xv.z * wv.z + xv.w * wv.w;
  }
  acc += __shfl_xor(acc, 1); acc += __shfl_xor(acc, 2); acc += __shfl_xor(acc, 4);
  if (l8 == 0){
    float r = sigm_f(acc + bs[0]);
    if (t < 16) out_vals[t * 32 + b] = r; else out_valid[b] = r;
  }
}

// ---------------- batched attn head-mean over all 16 steps ----------------
__global__ __launch_bounds__(256) void attnavg_all_k(const float* __restrict__ afull, float* __restrict__ out){
  int idx = blockIdx.x * 256 + threadIdx.x;     // 16*32768
  int t = idx >> 15, r = idx & 32767;
  int b = r >> 10, s = r & 1023;
  const float* base = afull + (size_t)t * 524288 + (size_t)b * 16384;
  float acc = 0.f;
  #pragma unroll
  for (int h = 0; h < 16; h++) acc += base[h * 1024 + s];
  out[idx] = acc * (1.f / 16.f);
}

extern "C" void kernel_launch(void* const* d_in, const int* in_sizes, int n_in,
                              void* d_out, int out_size, void* d_ws, size_t ws_size,
                              hipStream_t stream) {
  const float* comp      = (const float*)d_in[0];
  const float* rule_w1   = (const float*)d_in[2];
  const float* rule_b1   = (const float*)d_in[3];
  const float* rule_w2   = (const float*)d_in[4];
  const float* rule_b2   = (const float*)d_in[5];
  const float* rule_emb  = (const float*)d_in[6];
  const float* attn_in_w = (const float*)d_in[7];
  const float* attn_in_b = (const float*)d_in[8];
  const float* attn_out_w= (const float*)d_in[9];
  const float* attn_out_b= (const float*)d_in[10];
  const float* wih0 = (const float*)d_in[11];
  const float* whh0 = (const float*)d_in[12];
  const float* bih0 = (const float*)d_in[13];
  const float* bhh0 = (const float*)d_in[14];
  const float* wih1 = (const float*)d_in[15];
  const float* whh1 = (const float*)d_in[16];
  const float* bih1 = (const float*)d_in[17];
  const float* bhh1 = (const float*)d_in[18];
  const float* gen_w1 = (const float*)d_in[19];
  const float* gen_b1 = (const float*)d_in[20];
  const float* ln_g   = (const float*)d_in[21];
  const float* ln_b   = (const float*)d_in[22];
  const float* gen_w2 = (const float*)d_in[23];
  const float* gen_b2 = (const float*)d_in[24];
  const float* val_w1 = (const float*)d_in[25];
  const float* val_b1 = (const float*)d_in[26];
  const float* val_w2 = (const float*)d_in[27];
  const float* val_b2 = (const float*)d_in[28];
  const float* ver_w1 = (const float*)d_in[29];
  const float* ver_b1 = (const float*)d_in[30];
  const float* ver_w2 = (const float*)d_in[31];
  const float* ver_b2 = (const float*)d_in[32];

  float* out_f     = (float*)d_out;
  float* out_proof = out_f;                       // (17,32,1024)
  float* out_valid = out_f + 17 * 32768;          // (32,1)
  float* out_probs = out_valid + 32;              // (16,32,32)
  float* out_vals  = out_probs + 16 * 1024;       // (16,32,1)
  float* out_attn  = out_vals + 16 * 32;          // (16,32,1024)

  char* wp = (char*)d_ws;
  auto carve = [&](size_t bytes) -> void* {
    void* p = (void*)wp; wp += (bytes + 255) & ~(size_t)255; return p;
  };
  u16* Kt    = (u16*)carve((size_t)33554432 * 2);   // bf16 [b][hd][s]
  u16* Vb    = (u16*)carve((size_t)33554432 * 2);   // bf16 [b][h][s][d]
  u16* compb = (u16*)carve((size_t)33554432 * 2);   // bf16 comp; afull_all aliases after gemms
  float* afull_all = (float*)compb;                 // 16 * 512 * 1024 fp32 = 32MB
  u16* rw1b  = (u16*)carve(2097152);
  u16* wqb   = (u16*)carve(2097152);
  u16* wkb   = (u16*)carve(2097152);
  u16* wvb   = (u16*)carve(2097152);
  u16* aowTb = (u16*)carve(2097152);
  u16* wih0b = (u16*)carve(8388608);
  u16* whh0b = (u16*)carve(8388608);
  u16* wih1b = (u16*)carve(8388608);
  u16* whh1b = (u16*)carve(8388608);
  u16* gw1b  = (u16*)carve(4194304);
  u16* gw2b  = (u16*)carve(4194304);
  u16* vw1b  = (u16*)carve(4194304);
  u16* verw1b= (u16*)carve(2097152);
  u16* gaw   = (u16*)carve(4194304);                // gw1 @ aow
  float* bias2 = (float*)carve(8192);
  float* psa[2] = { (float*)carve(131072), (float*)carve(131072) };   // ps partial A
  float* psq[2] = { (float*)carve(131072), (float*)carve(131072) };   // ps partial B
  float* h0b[2] = { (float*)carve(131072), (float*)carve(131072) };
  float* c0b[2] = { (float*)carve(131072), (float*)carve(131072) };
  float* h1b[2] = { (float*)carve(131072), (float*)carve(131072) };
  float* c1b[2] = { (float*)carve(131072), (float*)carve(131072) };
  float* h1act = (float*)carve(131072);
  float* sel   = (float*)carve(131072);
  float* qbuf  = (float*)carve(131072);
  float* ctx0  = (float*)carve(131072);
  float* zbuf  = (float*)carve(262144);
  float* v1buf = (float*)carve(2228224);
  float* lnstats = (float*)carve(256);
  (void)ws_size; (void)in_sizes; (void)n_in; (void)out_size;

  // ---- casts (weights + comp in one launch) + transpose-cast ----
  CastJobs J;
  const float* srcs[13] = { rule_w1, attn_in_w, attn_in_w + 1048576, attn_in_w + 2097152,
                            wih0, whh0, wih1, whh1, gen_w1, gen_w2, val_w1, ver_w1, comp };
  u16* dsts[13] = { rw1b, wqb, wkb, wvb, wih0b, whh0b, wih1b, whh1b, gw1b, gw2b, vw1b, verw1b, compb };
  int sizes[13] = { 1048576, 1048576, 1048576, 1048576,
                    4194304, 4194304, 4194304, 4194304, 2097152, 2097152, 2097152, 1048576, 33554432 };
  int st = 0;
  for (int i = 0; i < 13; i++){ J.s[i] = srcs[i]; J.d[i] = dsts[i]; J.start[i] = st; st += sizes[i] / 1024; }
  J.start[13] = st;
  cast_all_k<<<dim3(st), dim3(256), 0, stream>>>(J);
  tcast_k<<<dim3(1024), dim3(256), 0, stream>>>(attn_out_w, aowTb);

  gemmkv_k<<<dim3(2048, 1, 2), dim3(256), 0, stream>>>(compb, wkb, wvb,
      attn_in_b + 1024, attn_in_b + 2048, Kt, Vb);
  gemmbb_k<<<dim3(16, 8), dim3(256), 0, stream>>>(gw1b, aowTb, gaw);
  bias2_k<<<dim3(64), dim3(256), 0, stream>>>(gen_w1, attn_out_b, gen_b1, bias2);

  init_k<<<dim3(128), dim3(256), 0, stream>>>(comp, psa[0], psq[0], out_proof,
      h0b[0], c0b[0], h1b[0], c1b[0]);

  for (int t = 0; t < 16; t++){
    int cur = t & 1, nx = cur ^ 1;
    float* pa = psa[cur];
    float* pb = psq[cur];
    float* afull_t = afull_all + (size_t)t * 524288;
    // D1: rule h1 (64) + q (64) + LSTM0 (256 gate tiles) + proof[t] fixup (32)
    LinSeg sRule = {}; sRule.X0 = pa; sRule.Xa = pb; sRule.K1 = 1024; sRule.ldx = 1024;
    sRule.W1 = rw1b; sRule.ld1 = 1024; sRule.b1 = rule_b1; sRule.out = h1act; sRule.N = 1024; sRule.act = 1;
    LinSeg sQ = {}; sQ.X0 = pa; sQ.Xa = pb; sQ.K1 = 1024; sQ.ldx = 1024;
    sQ.W1 = wqb; sQ.ld1 = 1024; sQ.b1 = attn_in_b; sQ.out = qbuf; sQ.N = 1024; sQ.act = 2; sQ.scale = 0.125f;
    LinSeg sL0 = {}; sL0.X0 = pa; sL0.Xa = pb; sL0.K1 = 1024; sL0.ldx = 1024;
    sL0.W1 = wih0b; sL0.ld1 = 1024; sL0.b1 = bih0;
    sL0.Y = h0b[cur]; sL0.K2 = 1024; sL0.W2 = whh0b; sL0.ld2 = 1024; sL0.b2 = bhh0;
    sL0.gate = 1; sL0.cprev = c0b[cur]; sL0.cout = c0b[nx]; sL0.hout = h0b[nx];
    step_d1_k<<<dim3(416), dim3(256), 0, stream>>>(sRule, sQ, sL0, pa, pb,
        out_proof + (size_t)t * 32768);
    // D2: attention + rule2 + LSTM1 + LN-stat zero
    D2Params P;
    P.qbuf = qbuf; P.Kt = Kt; P.Vb = Vb; P.afull = afull_t; P.ctx0 = ctx0;
    P.h1a = h1act; P.w2 = rule_w2; P.b2r = rule_b2; P.emb = rule_emb;
    P.probs_out = out_probs + t * 1024; P.sel = sel;
    LinSeg sL1 = {}; sL1.X0 = h0b[nx]; sL1.K1 = 1024; sL1.ldx = 1024;
    sL1.W1 = wih1b; sL1.ld1 = 1024; sL1.b1 = bih1;
    sL1.Y = h1b[cur]; sL1.K2 = 1024; sL1.W2 = whh1b; sL1.ld2 = 1024; sL1.b2 = bhh1;
    sL1.gate = 1; sL1.cprev = c1b[cur]; sL1.cout = c1b[nx]; sL1.hout = h1b[nx];
    P.sL1 = sL1; P.lnstats = lnstats;
    step_d2_k<<<dim3(801), dim3(256), 0, stream>>>(P);
    // D3: z = (ps_a+ps_b+sel+mem)@gw1^T + ctx0@gaw^T + bias2, LN stats (128 tiles)
    LinSeg sG1 = {}; sG1.X0 = pa; sG1.Xa = pb; sG1.Xb = sel; sG1.Xc = h1b[nx];
    sG1.K1 = 1024; sG1.ldx = 1024; sG1.W1 = gw1b; sG1.ld1 = 1024; sG1.b1 = bias2;
    sG1.Y = ctx0; sG1.K2 = 1024; sG1.W2 = gaw; sG1.ld2 = 1024;
    sG1.out = zbuf; sG1.N = 2048; sG1.stats = lnstats;
    linmulti_k<<<dim3(128), dim3(256), 0, stream>>>(sG1, sG1, sG1, 128, 0);
    // D4: psn = gelu(LN(z)) @ gw2^T + b, K-split x2 into partials (128 blocks)
    LinSeg sA = {}; sA.X0 = zbuf; sA.K1 = 1024; sA.ldx = 2048;
    sA.W1 = gw2b; sA.ld1 = 2048; sA.b1 = gen_b2;
    sA.lng = ln_g; sA.lnb = ln_b; sA.lnstats = lnstats;
    sA.out = psa[nx]; sA.N = 1024;
    LinSeg sB = {}; sB.X0 = zbuf + 1024; sB.K1 = 1024; sB.ldx = 2048;
    sB.W1 = gw2b + 1024; sB.ld1 = 2048;
    sB.lng = ln_g + 1024; sB.lnb = ln_b + 1024; sB.lnstats = lnstats;
    sB.out = psq[nx]; sB.N = 1024;
    linmulti_k<<<dim3(128), dim3(256), 0, stream>>>(sA, sB, sB, 64, 64);
  }
  // post-loop: proof[16] fixup, batched value heads + verifier, attn head-mean
  fixup_k<<<dim3(32), dim3(256), 0, stream>>>(psa[0], psq[0], out_proof + (size_t)16 * 32768);
  valver_k<<<dim3(64, 17), dim3(256), 0, stream>>>(vw1b, val_b1, verw1b, ver_b1,
      out_proof, psa[0], psq[0], v1buf);
  dotsig_b_k<<<dim3(17), dim3(256), 0, stream>>>(v1buf, val_w2, val_b2, ver_w2, ver_b2,
      out_vals, out_valid);
  attnavg_all_k<<<dim3(2048), dim3(256), 0, stream>>>(afull_all, out_attn);
}